// Round 9
// baseline (1145.389 us; speedup 1.0000x reference)
//
#include <hip/hip_runtime.h>
#include <stdint.h>

// Problem constants: B=128, S=256, H=512
#define B_ 128
#define S_ 256
#define H_ 512

typedef __attribute__((ext_vector_type(4))) float f32x4;
typedef __attribute__((ext_vector_type(4))) int i32x4;
typedef __attribute__((ext_vector_type(2))) unsigned int u32x2;
typedef __attribute__((ext_vector_type(8))) __bf16 bf16x8;
typedef unsigned long long u64;

// ---------- workspace layout (bytes) ----------
#define OFF_G      0          // G transposed [s][b]: 32768 f32 = 131072 B
#define OFF_RSR    131072     // 512 f32
#define OFF_RSH    133120     // 512 f32
#define OFF_FLG    135168     // 32 u32 flags (+pad to 4 KiB)
#define OFF_EX     139264     // 2 parity x 8 groups x 16 rows x 256 dw = 262144 B
#define OFF_CBUF   401408     // 128 x 512 f32 = 262144 B
#define OFF_BP     663552     // z1_w packed bf16 = 2097152 B
#define OFF_PB     2760704    // scan weights packed bf16 = 1048576 B
#define OFF_LOGITS 3809280    // 32768 f32 = 131072 B
// total ~3.94 MB

__device__ __forceinline__ unsigned short f2bf(float f) {
  unsigned u = __builtin_bit_cast(unsigned, f);
  u += 0x7FFFu + ((u >> 16) & 1u);
  return (unsigned short)(u >> 16);
}
__device__ __forceinline__ float fast_sigmoid(float x) {
  return 1.0f / (1.0f + __expf(-x));
}
__device__ __forceinline__ float fast_tanh(float x) {
  return 1.0f - 2.0f / (__expf(2.0f * x) + 1.0f);
}

// ---------------------------------------------------------------------------
// Merged prep kernel (one launch instead of three):
//  blk <2048 : pack z1_w -> Bp[(k>>3)*512+n][k&7]
//  blk <3072 : pack Ur,U -> PB (v7 layout: wave w owns ntile w, both matrices)
//  blk <3584 : row sums of Wr/W (2 rows per block, 256 threads each)
// ---------------------------------------------------------------------------
__global__ __launch_bounds__(512) void k_prep(
    const float* __restrict__ z1w, const float* __restrict__ Ur,
    const float* __restrict__ U, const float* __restrict__ Wr,
    const float* __restrict__ W, unsigned short* __restrict__ Bp,
    unsigned short* __restrict__ PB, float* __restrict__ rsr,
    float* __restrict__ rsh) {
  __shared__ float red[8];
  const int blk = blockIdx.x, tid = threadIdx.x;
  if (blk < 2048) {
    int t = blk * 512 + tid;  // < 2048*512
    int k = t >> 9, n = t & 511;
    Bp[((k >> 3) * 512 + n) * 8 + (k & 7)] = f2bf(z1w[t]);
  } else if (blk < 3072) {
    int t = (blk - 2048) * 512 + tid;  // < 524288
    int j = t & 7;
    int l = (t >> 3) & 63;
    int kt = (t >> 9) & 15;
    int mat = (t >> 13) & 1;
    int w = (t >> 14) & 7;
    int mem = t >> 17;  // 0..3
    int k = kt * 32 + ((l >> 4) & 3) * 8 + j;
    int n = mem * 128 + w * 16 + (l & 15);
    const float* src = mat ? U : Ur;
    PB[t] = f2bf(src[k * 512 + n]);
  } else {
    int h2 = (blk - 3072) * 2 + (tid >> 8);
    int t2 = tid & 255;
    const float* M = (h2 >= 512) ? W : Wr;
    int h = h2 & 511;
    float sv = M[h * 512 + t2] + M[h * 512 + 256 + t2];
#pragma unroll
    for (int mask = 1; mask < 64; mask <<= 1) sv += __shfl_xor(sv, mask, 64);
    if ((tid & 63) == 0) red[tid >> 6] = sv;
    __syncthreads();
    if (tid == 0) {
      float tot = red[0] + red[1] + red[2] + red[3];
      ((h2 >= 512) ? rsh : rsr)[h] = tot;
    } else if (tid == 256) {
      float tot = red[4] + red[5] + red[6] + red[7];
      int h2b = h2;  // this thread's h2 (tid>>8 == 1)
      ((h2b >= 512) ? rsh : rsr)[h2b & 511] = tot;
    }
  }
}

// ---------------------------------------------------------------------------
// Gate GEMM v2: M=128 rows/WG (one batch-half), N=512, K=2048 in BK=32.
// 256 WGs = 1/CU. 8 waves: wave w = (mgrp=w&3 -> 2 mtiles, ngrp=w>>2 -> 16
// ntiles); 32 MFMAs/wave per K-iter (2x R7's 16 -> barrier cost amortized).
// B staged via global_load_lds width=16; fused tanh + z2w-dot epilogue.
// ---------------------------------------------------------------------------
__global__ __launch_bounds__(512, 2) void k_gate(
    const float* __restrict__ facts, const float* __restrict__ questions,
    const float* __restrict__ prevM, const float* __restrict__ z1b,
    const float* __restrict__ z2w, const unsigned short* __restrict__ Bp,
    float* __restrict__ logits) {
  __shared__ float qS[512], mS[512], z1bS[512], z2wS[512];
  __shared__ unsigned short At[128 * 40];  // 128 rows x 32k, pitch 40 shorts
  __shared__ unsigned short Bt[16384];     // 32KB: one BK=32 chunk of Bp
  __shared__ float lp[128 * 2];
  const int tid = threadIdx.x;
  const int row0 = blockIdx.x * 128;  // = batch*256 + s0
  const int b = row0 >> 8;
  qS[tid] = questions[b * 512 + tid];
  mS[tid] = prevM[b * 512 + tid];
  z1bS[tid] = z1b[tid];
  z2wS[tid] = z2w[tid];
  const int w = tid >> 6, l = tid & 63;
  const int mgrp = w & 3, ngrp = w >> 2;
  const int lm = l & 15, lk = l >> 4;
  f32x4 acc[2][16];
#pragma unroll
  for (int a = 0; a < 2; ++a)
#pragma unroll
    for (int i = 0; i < 16; ++i) acc[a][i] = (f32x4){0.f, 0.f, 0.f, 0.f};
  const int arow = tid >> 2, ac = tid & 3;  // 128 rows, 8 k per thread
  const float* fbase = facts + (size_t)(row0 + arow) * 512 + ac * 8;

  for (int kb = 0; kb < 64; ++kb) {
    __syncthreads();
    // ---- async-stage B tile: 32 KB via 4 DMA instrs per wave ----
    {
      const char* gsrc = (const char*)Bp + (size_t)kb * 32768 + w * 4096 + l * 16;
#pragma unroll
      for (int i = 0; i < 4; ++i)
        __builtin_amdgcn_global_load_lds(
            (const __attribute__((address_space(1))) unsigned int*)(gsrc +
                                                                    i * 1024),
            (__attribute__((address_space(3))) unsigned int*)((char*)Bt +
                                                              w * 4096 +
                                                              i * 1024),
            16, 0, 0);
    }
    // ---- build A tile (128 rows x 32 k) in bf16 (overlaps DMA) ----
    const int part = kb >> 4;          // 0: f*q, 1: f*m, 2: |f-q|, 3: |f-m|
    const int h0 = (kb & 15) * 32;
    f32x4 fv0 = *(const f32x4*)(fbase + h0);
    f32x4 fv1 = *(const f32x4*)(fbase + h0 + 4);
    f32x4 ov0, ov1;
    if (part & 1) {
      ov0 = *(const f32x4*)&mS[h0 + ac * 8];
      ov1 = *(const f32x4*)&mS[h0 + ac * 8 + 4];
    } else {
      ov0 = *(const f32x4*)&qS[h0 + ac * 8];
      ov1 = *(const f32x4*)&qS[h0 + ac * 8 + 4];
    }
    float z[8];
    if (part < 2) {
#pragma unroll
      for (int i = 0; i < 4; ++i) {
        z[i] = fv0[i] * ov0[i];
        z[4 + i] = fv1[i] * ov1[i];
      }
    } else {
#pragma unroll
      for (int i = 0; i < 4; ++i) {
        z[i] = fabsf(fv0[i] - ov0[i]);
        z[4 + i] = fabsf(fv1[i] - ov1[i]);
      }
    }
    i32x4 pk;
#pragma unroll
    for (int i = 0; i < 4; ++i)
      pk[i] = (int)((unsigned)f2bf(z[2 * i]) |
                    ((unsigned)f2bf(z[2 * i + 1]) << 16));
    *(i32x4*)&At[arow * 40 + ac * 8] = pk;
    __syncthreads();  // drains DMA (vmcnt) + A-writes (lgkmcnt)
    // ---- fragments + MFMA: 2 mtiles x 16 ntiles per wave ----
    bf16x8 af[2];
#pragma unroll
    for (int mi = 0; mi < 2; ++mi) {
      i32x4 av = *(const i32x4*)&At[((mgrp * 2 + mi) * 16 + lm) * 40 + lk * 8];
      af[mi] = __builtin_bit_cast(bf16x8, av);
    }
#pragma unroll
    for (int i = 0; i < 16; ++i) {
      const int nt = ngrp * 16 + i;
      i32x4 bv = *(const i32x4*)&Bt[lk * 4096 + (nt * 16 + lm) * 8];
      bf16x8 bf = __builtin_bit_cast(bf16x8, bv);
      acc[0][i] = __builtin_amdgcn_mfma_f32_16x16x32_bf16(af[0], bf, acc[0][i], 0, 0, 0);
      acc[1][i] = __builtin_amdgcn_mfma_f32_16x16x32_bf16(af[1], bf, acc[1][i], 0, 0, 0);
    }
  }
  // ---- fused epilogue: tanh + dot(z2_w), reduce to per-row logits ----
  float pr_[2][4];
#pragma unroll
  for (int mi = 0; mi < 2; ++mi)
#pragma unroll
    for (int r = 0; r < 4; ++r) pr_[mi][r] = 0.f;
#pragma unroll
  for (int i = 0; i < 16; ++i) {
    const int n_i = (ngrp * 16 + i) * 16 + lm;
    const float zb = z1bS[n_i], zw = z2wS[n_i];
#pragma unroll
    for (int mi = 0; mi < 2; ++mi)
#pragma unroll
      for (int r = 0; r < 4; ++r)
        pr_[mi][r] += fast_tanh(acc[mi][i][r] + zb) * zw;
  }
#pragma unroll
  for (int mask = 1; mask < 16; mask <<= 1)
#pragma unroll
    for (int mi = 0; mi < 2; ++mi)
#pragma unroll
      for (int r = 0; r < 4; ++r)
        pr_[mi][r] += __shfl_xor(pr_[mi][r], mask, 64);
  if (lm == 0) {
#pragma unroll
    for (int mi = 0; mi < 2; ++mi)
#pragma unroll
      for (int r = 0; r < 4; ++r)
        lp[((mgrp * 2 + mi) * 16 + lk * 4 + r) * 2 + ngrp] = pr_[mi][r];
  }
  __syncthreads();
  if (tid < 128) logits[row0 + tid] = lp[tid * 2] + lp[tid * 2 + 1];
}

// ---------------------------------------------------------------------------
// Softmax over S per batch; output TRANSPOSED: GT[s][b]
// ---------------------------------------------------------------------------
__global__ void k_softmax(const float* __restrict__ logits,
                          float* __restrict__ GT) {
  __shared__ float red[4], red2[4];
  int b = blockIdx.x, t = threadIdx.x;
  float v = logits[b * 256 + t];
  float mx = v;
#pragma unroll
  for (int mask = 1; mask < 64; mask <<= 1)
    mx = fmaxf(mx, __shfl_xor(mx, mask, 64));
  if ((t & 63) == 0) red[t >> 6] = mx;
  __syncthreads();
  mx = fmaxf(fmaxf(red[0], red[1]), fmaxf(red[2], red[3]));
  float e = __expf(v - mx);
  float sm = e;
#pragma unroll
  for (int mask = 1; mask < 64; mask <<= 1) sm += __shfl_xor(sm, mask, 64);
  if ((t & 63) == 0) red2[t >> 6] = sm;
  __syncthreads();
  sm = red2[0] + red2[1] + red2[2] + red2[3];
  GT[t * 128 + b] = e / sm;
}

// ---------------------------------------------------------------------------
// Scan (R7 verbatim — known-passing): in-register update, 2 barriers/step.
// 8 groups x 4 members, 16 batches/group, N=128/WG, weights VGPR-resident.
// Chain: publish -> b1(drain) -> tid0 flag -> per-thread poll flag quad ->
// gather 3x8B -> b2. Agent-scope throughout (R8's sc0 experiment crashed:
// reverted; any future XCD-local retry must be placement-verified w/o
// inline-asm memory ops).
// ---------------------------------------------------------------------------
__global__ __launch_bounds__(512, 1) void k_scan(
    const float* __restrict__ facts, const float* __restrict__ GT,
    const unsigned short* __restrict__ PB, const float* __restrict__ rsr,
    const float* __restrict__ rsh, const float* __restrict__ br,
    const float* __restrict__ bur, const float* __restrict__ bw,
    const float* __restrict__ bu, unsigned int* __restrict__ EX,
    unsigned int* __restrict__ FLG, float* __restrict__ Cb) {
  __shared__ unsigned short A[16 * 520];  // 16 rows x 512 bf16, 1040B pitch
  const int tid = threadIdx.x;
  const int g = blockIdx.x & 7;    // group
  const int mem = blockIdx.x >> 3; // member 0..3, n-slice [mem*128, +128)
  const int w = tid >> 6, l = tid & 63;
  const int lm = l & 15, lk = (l >> 4) & 3;
  // zero A
  for (int i = tid; i < 16 * 520 / 4; i += 512) ((u64*)A)[i] = 0ull;
  // weights: wave w owns ntile w for BOTH matrices (128 VGPRs)
  i32x4 bfr[2][16];
  const char* pb = (const char*)PB + (size_t)(mem * 8 + w) * 32768;
#pragma unroll
  for (int mat = 0; mat < 2; ++mat)
#pragma unroll
    for (int kt = 0; kt < 16; ++kt)
      bfr[mat][kt] = *(const i32x4*)(pb + (mat * 16 + kt) * 1024 + l * 16);
  // this lane's (batch,n) in MFMA C/D layout
  const int n = mem * 128 + w * 16 + lm;
  const int b0 = g * 16 + lk * 4;  // batches b0..b0+3 (r = acc reg idx)
  const float c_rsr = rsr[n], c_br = br[n];
  const float c_rsh = rsh[n], c_bw = bw[n];
  const float c_bur = bur[n], c_bu = bu[n];
  const float* fb[4];
#pragma unroll
  for (int r = 0; r < 4; ++r)
    fb[r] = facts + (size_t)(b0 + r) * (256 * 512) + n;
  // gather mapping: thread covers (row = tid>>5, u64-unit = tid&31) per quad
  const int grow = tid >> 5, gcu = tid & 31;
  const u64* EXQ = (const u64*)EX;
  f32x4 Cv = (f32x4){0.f, 0.f, 0.f, 0.f};
  // prefetch s=0 inputs
  float fct[4];
#pragma unroll
  for (int r = 0; r < 4; ++r) fct[r] = fb[r][0];
  f32x4 gvv = *(const f32x4*)(GT + b0);
  __syncthreads();

  for (int s = 0; s < 256; ++s) {
    const unsigned tag = (unsigned)(s + 1);
    const unsigned rbase = ((unsigned)(s & 1) * 8 + (unsigned)g) * 16;
    // ---- matvec: acc0 = (C@Ur) tile, acc1 = (C@U) tile ----
    f32x4 acc0 = (f32x4){0.f, 0.f, 0.f, 0.f};
    f32x4 acc1 = (f32x4){0.f, 0.f, 0.f, 0.f};
#pragma unroll
    for (int kt = 0; kt < 16; ++kt) {
      i32x4 av = *(const i32x4*)&A[lm * 520 + kt * 32 + lk * 8];
      bf16x8 afv = __builtin_bit_cast(bf16x8, av);
      acc0 = __builtin_amdgcn_mfma_f32_16x16x32_bf16(
          afv, __builtin_bit_cast(bf16x8, bfr[0][kt]), acc0, 0, 0, 0);
      acc1 = __builtin_amdgcn_mfma_f32_16x16x32_bf16(
          afv, __builtin_bit_cast(bf16x8, bfr[1][kt]), acc1, 0, 0, 0);
    }
    // ---- in-register elementwise update (lane owns 4 batches x 1 n) ----
    unsigned pkd[4];
#pragma unroll
    for (int r = 0; r < 4; ++r) {
      const float pr = fct[r] * c_rsr + c_br;
      const float ph = fct[r] * c_rsh + c_bw;
      const float r_ = fast_sigmoid(pr + acc0[r] + c_bur);
      const float ht = fast_tanh(ph + r_ * (acc1[r] + c_bu));
      Cv[r] = gvv[r] * ht + (1.0f - gvv[r]) * Cv[r];
      const int mb = (int)f2bf(Cv[r]);
      pkd[r] = (unsigned)mb | ((unsigned)__shfl_xor(mb, 1, 64) << 16);
    }
    // ---- publish: even-n lanes store (n,n+1) dword per batch ----
    if (!(lm & 1)) {
#pragma unroll
      for (int r = 0; r < 4; ++r)
        __hip_atomic_store(EX + (rbase + (unsigned)(lk * 4 + r)) * 256 +
                               ((unsigned)n >> 1),
                           pkd[r], __ATOMIC_RELAXED, __HIP_MEMORY_SCOPE_AGENT);
    }
    // ---- prefetch next step's inputs (land during chain wait) ----
    float fctn[4];
    f32x4 gvn = gvv;
    if (s < 255) {
#pragma unroll
      for (int r = 0; r < 4; ++r) fctn[r] = fb[r][(size_t)(s + 1) * 512];
      gvn = *(const f32x4*)(GT + (s + 1) * 128 + b0);
    } else {
#pragma unroll
      for (int r = 0; r < 4; ++r) fctn[r] = 0.f;
    }
    __syncthreads();  // drains publish stores (vmcnt0); all MFMA A-reads done
    if (tid == 0)
      __hip_atomic_store(FLG + g * 4 + mem, tag, __ATOMIC_RELAXED,
                         __HIP_MEMORY_SCOPE_AGENT);
    // ---- own slice -> A (even-n lanes, 4B pairs) ----
    if (!(lm & 1)) {
#pragma unroll
      for (int r = 0; r < 4; ++r)
        *(unsigned*)((char*)A + (lk * 4 + r) * 1040 + n * 2) = pkd[r];
    }
    // ---- per-thread poll (1-line flag quad) + one-shot gather ----
    {
#pragma unroll
      for (int j = 0; j < 3; ++j) {
        const int q = j + (j >= mem ? 1 : 0);
        int guard = 0;
        while (__hip_atomic_load(FLG + g * 4 + q, __ATOMIC_RELAXED,
                                 __HIP_MEMORY_SCOPE_AGENT) < tag) {
          __builtin_amdgcn_s_sleep(1);
          if (++guard > (1 << 22)) break;  // hang-safety bailout
        }
      }
      u64 wv[3];
#pragma unroll
      for (int j = 0; j < 3; ++j) {
        const int q = j + (j >= mem ? 1 : 0);
        wv[j] = __hip_atomic_load(
            EXQ + (rbase + (unsigned)grow) * 128 + (unsigned)(q * 32 + gcu),
            __ATOMIC_RELAXED, __HIP_MEMORY_SCOPE_AGENT);
      }
#pragma unroll
      for (int j = 0; j < 3; ++j) {
        const int q = j + (j >= mem ? 1 : 0);
        *(u64*)((char*)A + grow * 1040 + q * 256 + gcu * 8) = wv[j];
      }
    }
    __syncthreads();  // A fully assembled for next step
#pragma unroll
    for (int r = 0; r < 4; ++r) fct[r] = fctn[r];
    gvv = gvn;
  }
#pragma unroll
  for (int r = 0; r < 4; ++r) Cb[(size_t)(b0 + r) * 512 + n] = Cv[r];
}

// ---------------------------------------------------------------------------
// Final: out[b] = relu([prevM | C | questions] @ nm_w + nm_b). 4 batches/WG
// (halves nm_w re-read traffic vs 2/WG).
// ---------------------------------------------------------------------------
__global__ __launch_bounds__(512) void k_final(
    const float* __restrict__ prevM, const float* __restrict__ questions,
    const float* __restrict__ Cb, const float* __restrict__ nmw,
    const float* __restrict__ nmb, float* __restrict__ out) {
  __shared__ float cc[4][1536];
  const int t = threadIdx.x;
  const int b0 = blockIdx.x * 4;
  for (int i = t; i < 1536; i += 512) {
#pragma unroll
    for (int bi = 0; bi < 4; ++bi) {
      int bbx = b0 + bi;
      float v;
      if (i < 512) v = prevM[bbx * 512 + i];
      else if (i < 1024) v = Cb[bbx * 512 + i - 512];
      else v = questions[bbx * 512 + i - 1024];
      cc[bi][i] = v;
    }
  }
  __syncthreads();
  const int h = t;
  float a0 = nmb[h], a1 = a0, a2 = a0, a3 = a0;
#pragma unroll 4
  for (int f = 0; f < 1536; ++f) {
    float wv = nmw[f * 512 + h];
    a0 = fmaf(cc[0][f], wv, a0);
    a1 = fmaf(cc[1][f], wv, a1);
    a2 = fmaf(cc[2][f], wv, a2);
    a3 = fmaf(cc[3][f], wv, a3);
  }
  out[(size_t)b0 * 512 + h] = fmaxf(a0, 0.f);
  out[(size_t)(b0 + 1) * 512 + h] = fmaxf(a1, 0.f);
  out[(size_t)(b0 + 2) * 512 + h] = fmaxf(a2, 0.f);
  out[(size_t)(b0 + 3) * 512 + h] = fmaxf(a3, 0.f);
}

// ---------------------------------------------------------------------------
extern "C" void kernel_launch(void* const* d_in, const int* in_sizes, int n_in,
                              void* d_out, int out_size, void* d_ws,
                              size_t ws_size, hipStream_t stream) {
  const float* facts     = (const float*)d_in[0];
  const float* questions = (const float*)d_in[1];
  const float* prevM     = (const float*)d_in[2];
  const float* z1w       = (const float*)d_in[3];
  const float* z1b       = (const float*)d_in[4];
  const float* z2w       = (const float*)d_in[5];
  // d_in[6] = z2_b: softmax shift-invariant, unused (exact)
  const float* Wr        = (const float*)d_in[7];
  const float* br        = (const float*)d_in[8];
  const float* Ur        = (const float*)d_in[9];
  const float* bur       = (const float*)d_in[10];
  const float* W         = (const float*)d_in[11];
  const float* bw        = (const float*)d_in[12];
  const float* U         = (const float*)d_in[13];
  const float* bu        = (const float*)d_in[14];
  const float* nmw       = (const float*)d_in[15];
  const float* nmb       = (const float*)d_in[16];

  char* ws = (char*)d_ws;
  float* GT            = (float*)(ws + OFF_G);
  float* rsr           = (float*)(ws + OFF_RSR);
  float* rsh           = (float*)(ws + OFF_RSH);
  unsigned* FLG        = (unsigned*)(ws + OFF_FLG);
  unsigned* EX         = (unsigned*)(ws + OFF_EX);
  float* Cb            = (float*)(ws + OFF_CBUF);
  float* logits        = (float*)(ws + OFF_LOGITS);
  unsigned short* Bp   = (unsigned short*)(ws + OFF_BP);
  unsigned short* PB   = (unsigned short*)(ws + OFF_PB);

  hipMemsetAsync(FLG, 0, 128, stream);
  k_prep<<<3584, 512, 0, stream>>>(z1w, Ur, U, Wr, W, Bp, PB, rsr, rsh);
  k_gate<<<256, 512, 0, stream>>>(facts, questions, prevM, z1b, z2w, Bp, logits);
  k_softmax<<<128, 256, 0, stream>>>(logits, GT);
  k_scan<<<32, 512, 0, stream>>>(facts, GT, PB, rsr, rsh, br, bur, bw, bu, EX,
                                 FLG, Cb);
  k_final<<<32, 512, 0, stream>>>(prevM, questions, Cb, nmw, nmb, (float*)d_out);
}